// Round 19
// baseline (8516.845 us; speedup 1.0000x reference)
//
#include <hip/hip_runtime.h>

// W8A8 static-quant linear, M=8192 K=4096 N=11008. out = fp32((xq@W^T + qb)*dq)
// Decode (validated R14-R18, absmax 0.5): x fp32[M,K]-C, W i32-widened i8
// [N,K]-C, dq f32[N], isc f32[1], qb i32[N], iof i32[1], out fp32[M,N]-C.
//
// R19 = ABLATION ROUND. Five schedules (575-678us) all null-to-negative ->
// models exhausted; decompose empirically (m164/m165 discipline).
// gemm_abl<0> = production (R16 skeleton, best known 575us) -> writes d_out.
// gemm_abl<1> = no-epilogue, K-loop x8, acc asm-sunk     (epilogue cost)
// gemm_abl<2> = <1> minus staging/vmcnt                  (staging cost)
// gemm_abl<3> = <2> minus ds_read (laundered reg frags)  (LDS-read cost)
// x8 inflation puts each ablation above 575us -> all visible in top-5 table.
// Decomposition: epi = V0 - V1/8; stage = (V1-V2)/8; dsread = (V2-V3)/8;
// barrier+MFMA floor = V3/8 (analytic MFMA floor = 168us).

#define MDIM 8192
#define KDIM 4096
#define NDIM 11008

#define BM 128
#define BN 128
#define BK 64
#define TM (MDIM / BM)      // 64
#define TN (NDIM / BN)      // 86
#define NWG (TM * TN)       // 5504
#define CPX (NWG / 8)       // 688
#define KSTEPS (KDIM / BK)  // 64

using int32x4  = __attribute__((ext_vector_type(4))) int;
using int32x16 = __attribute__((ext_vector_type(16))) int;
using floatx4  = __attribute__((ext_vector_type(4))) float;
using uint32x2 = __attribute__((ext_vector_type(2))) unsigned int;

__device__ __forceinline__ void gload_lds16(const void* g, void* l) {
    __builtin_amdgcn_global_load_lds(
        (__attribute__((address_space(1))) unsigned int*)g,
        (__attribute__((address_space(3))) unsigned int*)l,
        16, 0, 0);
}

__device__ __forceinline__ int quant1(float f, float inv, float off) {
    float r = rintf(f * inv) + off;          // jnp: round half-even, then clip
    r = fminf(127.f, fmaxf(-128.f, r));
    return (int)r;
}

__device__ __forceinline__ int pack4i(int a, int b, int c, int d) {
    return (a & 255) | ((b & 255) << 8) | ((c & 255) << 16) | ((d & 255) << 24);
}

struct Resolved { const float* dq; const int* qb; };
__device__ __forceinline__ Resolved resolve4(const void* p11a, const void* p11b) {
    Resolved r;
    int a_is_dq = 1;
#pragma unroll
    for (int j = 0; j < 8; ++j) {
        const float v = ((const float*)p11a)[j];
        a_is_dq &= (v > 1e-6f) & (v < 1e-2f);   // deq ~1e-4; int bits: denorm/neg
    }
    r.dq = a_is_dq ? (const float*)p11a : (const float*)p11b;
    r.qb = a_is_dq ? (const int*)p11b : (const int*)p11a;
    return r;
}

__device__ __forceinline__ void resolve_scale(const void* p1a, const void* p1b,
                                              float* inv, float* off) {
    const float fa = ((const float*)p1a)[0];
    const int a_is_isc = (fa > 1e-3f) & (fa < 1.0f);  // isc in [0.02,0.045]
    const float iscv = a_is_isc ? ((const float*)p1a)[0] : ((const float*)p1b)[0];
    *inv = 1.0f / iscv;
    *off = (float)(a_is_isc ? ((const int*)p1b)[0] : ((const int*)p1a)[0]);
}

// ---------------- pass 1a: x fp32 -> int8 ----------------
__global__ __launch_bounds__(256)
void quant_x(const float* __restrict__ X, const void* p1a, const void* p1b,
             signed char* __restrict__ xq) {
    float inv, off;
    resolve_scale(p1a, p1b, &inv, &off);
    const long long nch = (long long)MDIM * KDIM / 8;
    const long long stride = (long long)gridDim.x * 256;
    for (long long i = (long long)blockIdx.x * 256 + threadIdx.x; i < nch; i += stride) {
        floatx4 v0 = ((const floatx4*)X)[2 * i];
        floatx4 v1 = ((const floatx4*)X)[2 * i + 1];
        int q[8];
#pragma unroll
        for (int j = 0; j < 4; ++j) {
            q[j]     = quant1(v0[j], inv, off);
            q[4 + j] = quant1(v1[j], inv, off);
        }
        uint32x2 o;
        o[0] = (unsigned)pack4i(q[0], q[1], q[2], q[3]);
        o[1] = (unsigned)pack4i(q[4], q[5], q[6], q[7]);
        ((uint32x2*)xq)[i] = o;
    }
}

// ---------------- pass 1b: weight int32 -> int8 ----------------
__global__ __launch_bounds__(256)
void pack_w(const int* __restrict__ Wi, signed char* __restrict__ W8) {
    const long long nch = (long long)NDIM * KDIM / 8;
    const long long stride = (long long)gridDim.x * 256;
    for (long long i = (long long)blockIdx.x * 256 + threadIdx.x; i < nch; i += stride) {
        int32x4 a = ((const int32x4*)Wi)[2 * i];
        int32x4 b = ((const int32x4*)Wi)[2 * i + 1];
        uint32x2 o;
        o[0] = (unsigned)pack4i(a[0], a[1], a[2], a[3]);
        o[1] = (unsigned)pack4i(b[0], b[1], b[2], b[3]);
        ((uint32x2*)W8)[i] = o;
    }
}

// ---- pass 2: R16 skeleton, templated ablation ----
// V=0 full+store; V=1 no-store x8; V=2 no-stage x8; V=3 no-stage-no-dsread x8.
template <int V>
__global__ __launch_bounds__(256, 3)
void gemm_abl(const signed char* __restrict__ Aq, const signed char* __restrict__ W8,
              const void* p11a, const void* p11b,
              float* __restrict__ out) {
    __shared__ alignas(16) signed char As[3][BM * BK];   // 3 x 8KB
    __shared__ alignas(16) signed char Bs[3][BN * BK];   // 3 x 8KB

    const int tid  = threadIdx.x;
    const int lane = tid & 63;
    const int wv   = tid >> 6;
    const int l5   = lane >> 5;
    const int lr   = lane & 31;
    const int wm   = wv >> 1;
    const int wn   = wv & 1;

    const int bid = blockIdx.x;
    const int wg  = (bid & 7) * CPX + (bid >> 3);   // bijective XCD swizzle
    const int m0  = (wg & (TM - 1)) * BM;
    const int n0  = (wg >> 6) * BN;

    int32x16 acc[2][2];
#pragma unroll
    for (int i = 0; i < 2; ++i)
#pragma unroll
        for (int j = 0; j < 2; ++j)
#pragma unroll
            for (int e = 0; e < 16; ++e) acc[i][j][e] = 0;

    auto stage = [&](int buf, int kt) {
        const int kb = kt * BK;
#pragma unroll
        for (int j = 0; j < 2; ++j) {
            const int ci = (wv << 6) + (j << 8) + lane;
            const int r  = ci >> 2;
            const int p  = ci & 3;
            const int c  = p ^ ((r >> 1) & 3);      // inverse swizzle on source
            gload_lds16(Aq + (size_t)(m0 + r) * KDIM + kb + (c << 4),
                        &As[buf][((wv << 6) + (j << 8)) << 4]);
            gload_lds16(W8 + (size_t)(n0 + r) * KDIM + kb + (c << 4),
                        &Bs[buf][((wv << 6) + (j << 8)) << 4]);
        }
    };

    // V=3: loop-invariant laundered register fragments (rule #17: asm keeps
    // them opaque so neither the frags nor the MFMAs can be folded/DCE'd).
    int32x4 cf[2], cg[2];
    if constexpr (V == 3) {
#pragma unroll
        for (int i = 0; i < 2; ++i) {
#pragma unroll
            for (int e = 0; e < 4; ++e) {
                int t0 = lane * 8 + i * 4 + e;
                asm volatile("" : "+v"(t0));
                cf[i][e] = t0;
                int t1 = lane * 8 + i * 4 + e + 101;
                asm volatile("" : "+v"(t1));
                cg[i][e] = t1;
            }
        }
    }

    constexpr int REPS = (V == 0) ? 1 : 8;
    for (int rep = 0; rep < REPS; ++rep) {
        if constexpr (V <= 1) {
            stage(0, 0);
            stage(1, 1);
        }
        int cur = 0, nb2 = 2;
        for (int kt = 0; kt < KSTEPS; ++kt) {
            if constexpr (V <= 1) {
                if (kt + 2 < KSTEPS) {
                    stage(nb2, kt + 2);
                    asm volatile("s_waitcnt vmcnt(8)" ::: "memory");
                } else if (kt + 1 < KSTEPS) {
                    asm volatile("s_waitcnt vmcnt(4)" ::: "memory");
                } else {
                    asm volatile("s_waitcnt vmcnt(0)" ::: "memory");
                }
            }
            __builtin_amdgcn_s_barrier();
            __builtin_amdgcn_sched_barrier(0);

            const signed char* Ab = As[cur];
            const signed char* Bb = Bs[cur];
            __builtin_amdgcn_s_setprio(1);
#pragma unroll
            for (int ks = 0; ks < 2; ++ks) {
                int32x4 af[2], bf[2];
                if constexpr (V <= 2) {
#pragma unroll
                    for (int mt = 0; mt < 2; ++mt) {
                        const int r = wm * 64 + mt * 32 + lr;
                        const int p = (ks * 2 + l5) ^ ((r >> 1) & 3);
                        af[mt] = *(const int32x4*)(Ab + (r << 6) + (p << 4));
                    }
#pragma unroll
                    for (int nt = 0; nt < 2; ++nt) {
                        const int r = wn * 64 + nt * 32 + lr;
                        const int p = (ks * 2 + l5) ^ ((r >> 1) & 3);
                        bf[nt] = *(const int32x4*)(Bb + (r << 6) + (p << 4));
                    }
                } else {
                    af[0] = cf[0]; af[1] = cf[1];
                    bf[0] = cg[0]; bf[1] = cg[1];
                }
#pragma unroll
                for (int mt = 0; mt < 2; ++mt)
#pragma unroll
                    for (int nt = 0; nt < 2; ++nt)
                        acc[mt][nt] = __builtin_amdgcn_mfma_i32_32x32x32_i8(
                            af[mt], bf[nt], acc[mt][nt], 0, 0, 0);
            }
            __builtin_amdgcn_s_setprio(0);
            __builtin_amdgcn_s_barrier();

            cur = (cur == 2) ? 0 : cur + 1;
            nb2 = (nb2 == 2) ? 0 : nb2 + 1;
        }
    }

    if constexpr (V == 0) {
        // epilogue: (acc + qb[n]) * dq[n] -> fp32, C-order [M,N]
        // C/D layout: col = lane&31, row = (reg&3)+8*(reg>>2)+4*(lane>>5)
        const Resolved rs = resolve4(p11a, p11b);
#pragma unroll
        for (int nt = 0; nt < 2; ++nt) {
            const int gn   = n0 + wn * 64 + nt * 32 + lr;
            const int qbn  = rs.qb[gn];
            const float dq = rs.dq[gn];
#pragma unroll
            for (int mt = 0; mt < 2; ++mt) {
                const int gmb = m0 + wm * 64 + mt * 32 + (l5 << 2);
#pragma unroll
                for (int v = 0; v < 16; ++v) {
                    const int gm = gmb + (v & 3) + ((v >> 2) << 3);
                    out[(size_t)gm * NDIM + gn] = (float)(acc[mt][nt][v] + qbn) * dq;
                }
            }
        }
    } else {
        // asm sink: keep every acc element live without stores (rule #17)
#pragma unroll
        for (int i = 0; i < 2; ++i)
#pragma unroll
            for (int j = 0; j < 2; ++j)
#pragma unroll
                for (int e = 0; e < 16; ++e)
                    asm volatile("" :: "v"(acc[i][j][e]));
    }
}

__global__ void codek(float* __restrict__ out) {
    out[blockIdx.x * 64 + threadIdx.x] = 51200.f;
}

extern "C" void kernel_launch(void* const* d_in, const int* in_sizes, int n_in,
                              void* d_out, int out_size, void* d_ws, size_t ws_size,
                              hipStream_t stream) {
    float* out = (float*)d_out;

    // order-robust pointer resolution by size fingerprint
    int ix = -1, iw = -1, i11[2] = {-1, -1}, i1[2] = {-1, -1};
    int n11 = 0, n1 = 0;
    bool bad = (n_in != 6);
    for (int i = 0; i < n_in && !bad; ++i) {
        const int s = in_sizes[i];
        if (s == MDIM * KDIM && ix < 0) ix = i;
        else if (s == NDIM * KDIM && iw < 0) iw = i;
        else if (s == NDIM && n11 < 2) i11[n11++] = i;
        else if (s == 1 && n1 < 2) i1[n1++] = i;
        else bad = true;
    }
    const size_t xq_bytes = (size_t)MDIM * KDIM;  // 33.5 MB
    const size_t w8_bytes = (size_t)NDIM * KDIM;  // 45.1 MB
    if (bad || ix < 0 || iw < 0 || n11 != 2 || n1 != 2 ||
        ws_size < xq_bytes + w8_bytes) {
        codek<<<dim3(100), dim3(64), 0, stream>>>(out);
        return;
    }

    const float* X  = (const float*)d_in[ix];
    const int*   Wi = (const int*)d_in[iw];
    const void*  pa = d_in[i11[0]];
    const void*  pb = d_in[i11[1]];
    const void*  pc = d_in[i1[0]];
    const void*  pd = d_in[i1[1]];

    signed char* xq = (signed char*)d_ws;
    signed char* w8 = xq + xq_bytes;

    quant_x<<<dim3(2048), dim3(256), 0, stream>>>(X, pc, pd, xq);
    pack_w<<<dim3(2048), dim3(256), 0, stream>>>(Wi, w8);
    // production output
    gemm_abl<0><<<dim3(NWG), dim3(256), 0, stream>>>(xq, w8, pa, pb, out);
    // ablations (no d_out writes; x8 K-loop so each lands in the top-5 table)
    gemm_abl<1><<<dim3(NWG), dim3(256), 0, stream>>>(xq, w8, pa, pb, out);
    gemm_abl<2><<<dim3(NWG), dim3(256), 0, stream>>>(xq, w8, pa, pb, out);
    gemm_abl<3><<<dim3(NWG), dim3(256), 0, stream>>>(xq, w8, pa, pb, out);
}

// Round 20
// 599.249 us; speedup vs baseline: 14.2125x; 14.2125x over previous
//
#include <hip/hip_runtime.h>

// W8A8 static-quant linear, M=8192 K=4096 N=11008. out = fp32((xq@W^T + qb)*dq)
// Decode (validated R14-R19, absmax 0.5): x fp32[M,K]-C, W i32-widened i8
// [N,K]-C, dq f32[N], isc f32[1], qb i32[N], iof i32[1], out fp32[M,N]-C.
//
// R19 ablation decomposition (x8 ablations, MFMA floor 168us/rep):
//   V1 (stage+dsread+MFMA+barriers) = 647us/rep
//   V2+V3 (no staging)              = ~168us/rep EACH (= MFMA floor)
//   => staging path = 480us = 74% of kernel; ds_read/barriers/epilogue ~free.
// FETCH 1.44GB vs 79MB ideal (18x over-fetch): m-fastest mapping makes
// co-resident blocks span all 64 A-panels -> L2 never hits on A.
// R20 = grouped tile mapping ONLY (single change vs R16's 575us):
// strips of 8 n-tiles, groups of 8 m-tiles, n-fastest inside a group ->
// w consecutive blocks read the IDENTICAL A panel; per-group active
// K-slice bytes ~128KB -> L2-resident.

#define MDIM 8192
#define KDIM 4096
#define NDIM 11008

#define BM 128
#define BN 128
#define BK 64
#define TM (MDIM / BM)      // 64
#define TN (NDIM / BN)      // 86
#define NWG (TM * TN)       // 5504
#define CPX (NWG / 8)       // 688
#define KSTEPS (KDIM / BK)  // 64

using int32x4  = __attribute__((ext_vector_type(4))) int;
using int32x16 = __attribute__((ext_vector_type(16))) int;
using floatx4  = __attribute__((ext_vector_type(4))) float;
using uint32x2 = __attribute__((ext_vector_type(2))) unsigned int;

__device__ __forceinline__ void gload_lds16(const void* g, void* l) {
    __builtin_amdgcn_global_load_lds(
        (__attribute__((address_space(1))) unsigned int*)g,
        (__attribute__((address_space(3))) unsigned int*)l,
        16, 0, 0);
}

__device__ __forceinline__ int quant1(float f, float inv, float off) {
    float r = rintf(f * inv) + off;          // jnp: round half-even, then clip
    r = fminf(127.f, fmaxf(-128.f, r));
    return (int)r;
}

__device__ __forceinline__ int pack4i(int a, int b, int c, int d) {
    return (a & 255) | ((b & 255) << 8) | ((c & 255) << 16) | ((d & 255) << 24);
}

struct Resolved { const float* dq; const int* qb; };
__device__ __forceinline__ Resolved resolve4(const void* p11a, const void* p11b) {
    Resolved r;
    int a_is_dq = 1;
#pragma unroll
    for (int j = 0; j < 8; ++j) {
        const float v = ((const float*)p11a)[j];
        a_is_dq &= (v > 1e-6f) & (v < 1e-2f);   // deq ~1e-4; int bits: denorm/neg
    }
    r.dq = a_is_dq ? (const float*)p11a : (const float*)p11b;
    r.qb = a_is_dq ? (const int*)p11b : (const int*)p11a;
    return r;
}

__device__ __forceinline__ void resolve_scale(const void* p1a, const void* p1b,
                                              float* inv, float* off) {
    const float fa = ((const float*)p1a)[0];
    const int a_is_isc = (fa > 1e-3f) & (fa < 1.0f);  // isc in [0.02,0.045]
    const float iscv = a_is_isc ? ((const float*)p1a)[0] : ((const float*)p1b)[0];
    *inv = 1.0f / iscv;
    *off = (float)(a_is_isc ? ((const int*)p1b)[0] : ((const int*)p1a)[0]);
}

// ---------------- pass 1a: x fp32 -> int8 ----------------
__global__ __launch_bounds__(256)
void quant_x(const float* __restrict__ X, const void* p1a, const void* p1b,
             signed char* __restrict__ xq) {
    float inv, off;
    resolve_scale(p1a, p1b, &inv, &off);
    const long long nch = (long long)MDIM * KDIM / 8;
    const long long stride = (long long)gridDim.x * 256;
    for (long long i = (long long)blockIdx.x * 256 + threadIdx.x; i < nch; i += stride) {
        floatx4 v0 = ((const floatx4*)X)[2 * i];
        floatx4 v1 = ((const floatx4*)X)[2 * i + 1];
        int q[8];
#pragma unroll
        for (int j = 0; j < 4; ++j) {
            q[j]     = quant1(v0[j], inv, off);
            q[4 + j] = quant1(v1[j], inv, off);
        }
        uint32x2 o;
        o[0] = (unsigned)pack4i(q[0], q[1], q[2], q[3]);
        o[1] = (unsigned)pack4i(q[4], q[5], q[6], q[7]);
        ((uint32x2*)xq)[i] = o;
    }
}

// ---------------- pass 1b: weight int32 -> int8 ----------------
__global__ __launch_bounds__(256)
void pack_w(const int* __restrict__ Wi, signed char* __restrict__ W8) {
    const long long nch = (long long)NDIM * KDIM / 8;
    const long long stride = (long long)gridDim.x * 256;
    for (long long i = (long long)blockIdx.x * 256 + threadIdx.x; i < nch; i += stride) {
        int32x4 a = ((const int32x4*)Wi)[2 * i];
        int32x4 b = ((const int32x4*)Wi)[2 * i + 1];
        uint32x2 o;
        o[0] = (unsigned)pack4i(a[0], a[1], a[2], a[3]);
        o[1] = (unsigned)pack4i(b[0], b[1], b[2], b[3]);
        ((uint32x2*)W8)[i] = o;
    }
}

// -- pass 2: int8 MFMA GEMM, R16 skeleton + grouped tile mapping --
// LDS per buffer: row r x 4 phys 16B chunks; logical chunk c at phys
// p = c ^ ((r>>1)&3); inverse swizzle on the global source (rule #21).
__global__ __launch_bounds__(256, 3)
void gemm_i8(const signed char* __restrict__ Aq, const signed char* __restrict__ W8,
             const void* p11a, const void* p11b,
             float* __restrict__ out) {
    __shared__ alignas(16) signed char As[3][BM * BK];   // 3 x 8KB
    __shared__ alignas(16) signed char Bs[3][BN * BK];   // 3 x 8KB

    const int tid  = threadIdx.x;
    const int lane = tid & 63;
    const int wv   = tid >> 6;
    const int l5   = lane >> 5;
    const int lr   = lane & 31;
    const int wm   = wv >> 1;
    const int wn   = wv & 1;

    const int bid = blockIdx.x;
    const int wg  = (bid & 7) * CPX + (bid >> 3);   // bijective XCD chunking
    // grouped mapping: strips of 8 n-tiles (last strip 6 since 86 = 10*8+6);
    // within a strip, groups of 8 m-tiles; within a group, n fastest.
    int s, r;
    if (wg < 5120) { s = wg >> 9; r = wg & 511; }   // strips 0..9: 512 wg each
    else           { s = 10;      r = wg - 5120; }  // strip 10: 384 wg
    const int w  = (s < 10) ? 8 : 6;                // strip width in n-tiles
    const int gs = w << 3;                          // group size = 8m * w
    const int g  = r / gs;                          // m-group 0..7
    const int t  = r % gs;
    const int m0 = ((g << 3) + t / w) * BM;
    const int n0 = (s * 8 + t % w) * BN;

    int32x16 acc[2][2];
#pragma unroll
    for (int i = 0; i < 2; ++i)
#pragma unroll
        for (int j = 0; j < 2; ++j)
#pragma unroll
            for (int e = 0; e < 16; ++e) acc[i][j][e] = 0;

    auto stage = [&](int buf, int kt) {
        const int kb = kt * BK;
#pragma unroll
        for (int j = 0; j < 2; ++j) {
            const int ci = (wv << 6) + (j << 8) + lane;
            const int rr = ci >> 2;
            const int pp = ci & 3;
            const int cc = pp ^ ((rr >> 1) & 3);    // inverse swizzle on source
            gload_lds16(Aq + (size_t)(m0 + rr) * KDIM + kb + (cc << 4),
                        &As[buf][((wv << 6) + (j << 8)) << 4]);
            gload_lds16(W8 + (size_t)(n0 + rr) * KDIM + kb + (cc << 4),
                        &Bs[buf][((wv << 6) + (j << 8)) << 4]);
        }
    };

    stage(0, 0);
    stage(1, 1);

    int cur = 0, nb2 = 2;
    for (int kt = 0; kt < KSTEPS; ++kt) {
        if (kt + 2 < KSTEPS) {
            stage(nb2, kt + 2);
            asm volatile("s_waitcnt vmcnt(8)" ::: "memory");
        } else if (kt + 1 < KSTEPS) {
            asm volatile("s_waitcnt vmcnt(4)" ::: "memory");
        } else {
            asm volatile("s_waitcnt vmcnt(0)" ::: "memory");
        }
        __builtin_amdgcn_s_barrier();
        __builtin_amdgcn_sched_barrier(0);

        const signed char* Ab = As[cur];
        const signed char* Bb = Bs[cur];
        __builtin_amdgcn_s_setprio(1);
#pragma unroll
        for (int ks = 0; ks < 2; ++ks) {
            int32x4 af[2], bf[2];
#pragma unroll
            for (int mt = 0; mt < 2; ++mt) {
                const int rr = wm * 64 + mt * 32 + lr;
                const int pp = (ks * 2 + l5) ^ ((rr >> 1) & 3);
                af[mt] = *(const int32x4*)(Ab + (rr << 6) + (pp << 4));
            }
#pragma unroll
            for (int nt = 0; nt < 2; ++nt) {
                const int rr = wn * 64 + nt * 32 + lr;
                const int pp = (ks * 2 + l5) ^ ((rr >> 1) & 3);
                bf[nt] = *(const int32x4*)(Bb + (rr << 6) + (pp << 4));
            }
#pragma unroll
            for (int mt = 0; mt < 2; ++mt)
#pragma unroll
                for (int nt = 0; nt < 2; ++nt)
                    acc[mt][nt] = __builtin_amdgcn_mfma_i32_32x32x32_i8(
                        af[mt], bf[nt], acc[mt][nt], 0, 0, 0);
        }
        __builtin_amdgcn_s_setprio(0);
        __builtin_amdgcn_s_barrier();

        cur = (cur == 2) ? 0 : cur + 1;
        nb2 = (nb2 == 2) ? 0 : nb2 + 1;
    }

    // epilogue: (acc + qb[n]) * dq[n] -> fp32, C-order [M,N]
    // C/D layout (HW-verified): col = lane&31, row = (reg&3)+8*(reg>>2)+4*(lane>>5)
    const Resolved rs = resolve4(p11a, p11b);
#pragma unroll
    for (int nt = 0; nt < 2; ++nt) {
        const int gn   = n0 + wn * 64 + nt * 32 + lr;
        const int qbn  = rs.qb[gn];
        const float dq = rs.dq[gn];
#pragma unroll
        for (int mt = 0; mt < 2; ++mt) {
            const int gmb = m0 + wm * 64 + mt * 32 + (l5 << 2);
#pragma unroll
            for (int v = 0; v < 16; ++v) {
                const int gm = gmb + (v & 3) + ((v >> 2) << 3);
                out[(size_t)gm * NDIM + gn] = (float)(acc[mt][nt][v] + qbn) * dq;
            }
        }
    }
}

__global__ void codek(float* __restrict__ out) {
    out[blockIdx.x * 64 + threadIdx.x] = 51200.f;
}

extern "C" void kernel_launch(void* const* d_in, const int* in_sizes, int n_in,
                              void* d_out, int out_size, void* d_ws, size_t ws_size,
                              hipStream_t stream) {
    float* out = (float*)d_out;

    // order-robust pointer resolution by size fingerprint
    int ix = -1, iw = -1, i11[2] = {-1, -1}, i1[2] = {-1, -1};
    int n11 = 0, n1 = 0;
    bool bad = (n_in != 6);
    for (int i = 0; i < n_in && !bad; ++i) {
        const int s = in_sizes[i];
        if (s == MDIM * KDIM && ix < 0) ix = i;
        else if (s == NDIM * KDIM && iw < 0) iw = i;
        else if (s == NDIM && n11 < 2) i11[n11++] = i;
        else if (s == 1 && n1 < 2) i1[n1++] = i;
        else bad = true;
    }
    const size_t xq_bytes = (size_t)MDIM * KDIM;  // 33.5 MB
    const size_t w8_bytes = (size_t)NDIM * KDIM;  // 45.1 MB
    if (bad || ix < 0 || iw < 0 || n11 != 2 || n1 != 2 ||
        ws_size < xq_bytes + w8_bytes) {
        codek<<<dim3(100), dim3(64), 0, stream>>>(out);
        return;
    }

    const float* X  = (const float*)d_in[ix];
    const int*   Wi = (const int*)d_in[iw];
    const void*  pa = d_in[i11[0]];
    const void*  pb = d_in[i11[1]];
    const void*  pc = d_in[i1[0]];
    const void*  pd = d_in[i1[1]];

    signed char* xq = (signed char*)d_ws;
    signed char* w8 = xq + xq_bytes;

    quant_x<<<dim3(2048), dim3(256), 0, stream>>>(X, pc, pd, xq);
    pack_w<<<dim3(2048), dim3(256), 0, stream>>>(Wi, w8);
    gemm_i8<<<dim3(NWG), dim3(256), 0, stream>>>(xq, w8, pa, pb, out);
}

// Round 21
// 593.970 us; speedup vs baseline: 14.3389x; 1.0089x over previous
//
#include <hip/hip_runtime.h>

// W8A8 static-quant linear, M=8192 K=4096 N=11008. out = fp32((xq@W^T + qb)*dq)
// Decode (validated R14-R20, absmax 0.5): x fp32[M,K]-C, W i32-widened i8
// [N,K]-C, dq f32[N], isc f32[1], qb i32[N], iof i32[1], out fp32[M,N]-C.
//
// Evidence: R19 ablation -> staging = 74% of kernel; R20 grouped mapping cut
// HBM fetch 3.5x but only -45us -> traffic not the pacer. Staging throughput
// is pinned at ~48B/cyc/CU across 4 different schedules -> suspect the
// global_load_lds LDS-DMA write path (never varied) vs per-CU L2 share.
// R21 = swap staging mechanism ONLY: reg-staged global_load -> ds_write_b128
// (normal 128B/clk LDS port), depth-1 reg pipeline, 2 LDS buffers, ONE
// barrier per K-step. Addressing/data placement byte-identical to R20.

#define MDIM 8192
#define KDIM 4096
#define NDIM 11008

#define BM 128
#define BN 128
#define BK 64
#define TM (MDIM / BM)      // 64
#define TN (NDIM / BN)      // 86
#define NWG (TM * TN)       // 5504
#define CPX (NWG / 8)       // 688
#define KSTEPS (KDIM / BK)  // 64

using int32x4  = __attribute__((ext_vector_type(4))) int;
using int32x16 = __attribute__((ext_vector_type(16))) int;
using floatx4  = __attribute__((ext_vector_type(4))) float;
using uint32x2 = __attribute__((ext_vector_type(2))) unsigned int;

__device__ __forceinline__ int quant1(float f, float inv, float off) {
    float r = rintf(f * inv) + off;          // jnp: round half-even, then clip
    r = fminf(127.f, fmaxf(-128.f, r));
    return (int)r;
}

__device__ __forceinline__ int pack4i(int a, int b, int c, int d) {
    return (a & 255) | ((b & 255) << 8) | ((c & 255) << 16) | ((d & 255) << 24);
}

struct Resolved { const float* dq; const int* qb; };
__device__ __forceinline__ Resolved resolve4(const void* p11a, const void* p11b) {
    Resolved r;
    int a_is_dq = 1;
#pragma unroll
    for (int j = 0; j < 8; ++j) {
        const float v = ((const float*)p11a)[j];
        a_is_dq &= (v > 1e-6f) & (v < 1e-2f);   // deq ~1e-4; int bits: denorm/neg
    }
    r.dq = a_is_dq ? (const float*)p11a : (const float*)p11b;
    r.qb = a_is_dq ? (const int*)p11b : (const int*)p11a;
    return r;
}

__device__ __forceinline__ void resolve_scale(const void* p1a, const void* p1b,
                                              float* inv, float* off) {
    const float fa = ((const float*)p1a)[0];
    const int a_is_isc = (fa > 1e-3f) & (fa < 1.0f);  // isc in [0.02,0.045]
    const float iscv = a_is_isc ? ((const float*)p1a)[0] : ((const float*)p1b)[0];
    *inv = 1.0f / iscv;
    *off = (float)(a_is_isc ? ((const int*)p1b)[0] : ((const int*)p1a)[0]);
}

// ---------------- pass 1a: x fp32 -> int8 ----------------
__global__ __launch_bounds__(256)
void quant_x(const float* __restrict__ X, const void* p1a, const void* p1b,
             signed char* __restrict__ xq) {
    float inv, off;
    resolve_scale(p1a, p1b, &inv, &off);
    const long long nch = (long long)MDIM * KDIM / 8;
    const long long stride = (long long)gridDim.x * 256;
    for (long long i = (long long)blockIdx.x * 256 + threadIdx.x; i < nch; i += stride) {
        floatx4 v0 = ((const floatx4*)X)[2 * i];
        floatx4 v1 = ((const floatx4*)X)[2 * i + 1];
        int q[8];
#pragma unroll
        for (int j = 0; j < 4; ++j) {
            q[j]     = quant1(v0[j], inv, off);
            q[4 + j] = quant1(v1[j], inv, off);
        }
        uint32x2 o;
        o[0] = (unsigned)pack4i(q[0], q[1], q[2], q[3]);
        o[1] = (unsigned)pack4i(q[4], q[5], q[6], q[7]);
        ((uint32x2*)xq)[i] = o;
    }
}

// ---------------- pass 1b: weight int32 -> int8 ----------------
__global__ __launch_bounds__(256)
void pack_w(const int* __restrict__ Wi, signed char* __restrict__ W8) {
    const long long nch = (long long)NDIM * KDIM / 8;
    const long long stride = (long long)gridDim.x * 256;
    for (long long i = (long long)blockIdx.x * 256 + threadIdx.x; i < nch; i += stride) {
        int32x4 a = ((const int32x4*)Wi)[2 * i];
        int32x4 b = ((const int32x4*)Wi)[2 * i + 1];
        uint32x2 o;
        o[0] = (unsigned)pack4i(a[0], a[1], a[2], a[3]);
        o[1] = (unsigned)pack4i(b[0], b[1], b[2], b[3]);
        ((uint32x2*)W8)[i] = o;
    }
}

// -- pass 2: int8 MFMA GEMM, reg-staged depth-1 pipeline, grouped mapping --
// LDS per buffer: row r x 4 phys 16B chunks; logical chunk c at phys
// p = c ^ ((r>>1)&3). Thread reads global chunk c (inverse swizzle on the
// source address) and ds_writes it to its LINEAR slot -> LDS image identical
// to the validated gload_lds version.
__global__ __launch_bounds__(256, 3)
void gemm_i8(const signed char* __restrict__ Aq, const signed char* __restrict__ W8,
             const void* p11a, const void* p11b,
             float* __restrict__ out) {
    __shared__ alignas(16) signed char As[2][BM * BK];   // 2 x 8KB
    __shared__ alignas(16) signed char Bs[2][BN * BK];   // 2 x 8KB

    const int tid  = threadIdx.x;
    const int lane = tid & 63;
    const int wv   = tid >> 6;
    const int l5   = lane >> 5;
    const int lr   = lane & 31;
    const int wm   = wv >> 1;
    const int wn   = wv & 1;

    const int bid = blockIdx.x;
    const int wg  = (bid & 7) * CPX + (bid >> 3);   // bijective XCD chunking
    // grouped mapping (R20-validated): strips of 8 n-tiles (last 6), groups
    // of 8 m-tiles, n fastest inside a group.
    int s, r;
    if (wg < 5120) { s = wg >> 9; r = wg & 511; }
    else           { s = 10;      r = wg - 5120; }
    const int w  = (s < 10) ? 8 : 6;
    const int gs = w << 3;
    const int g  = r / gs;
    const int t  = r % gs;
    const int m0 = ((g << 3) + t / w) * BM;
    const int n0 = (s * 8 + t % w) * BN;

    int32x16 acc[2][2];
#pragma unroll
    for (int i = 0; i < 2; ++i)
#pragma unroll
        for (int j = 0; j < 2; ++j)
#pragma unroll
            for (int e = 0; e < 16; ++e) acc[i][j][e] = 0;

    // per-thread staging geometry (2 chunks per operand, same as R20)
    int lofs[2];
    size_t gaofs[2], gbofs[2];
#pragma unroll
    for (int j = 0; j < 2; ++j) {
        const int ci = (wv << 6) + (j << 8) + lane;
        const int rr = ci >> 2;
        const int pp = ci & 3;
        const int cc = pp ^ ((rr >> 1) & 3);       // inverse swizzle on source
        lofs[j]  = ci << 4;
        gaofs[j] = (size_t)(m0 + rr) * KDIM + (cc << 4);
        gbofs[j] = (size_t)(n0 + rr) * KDIM + (cc << 4);
    }

    int32x4 pa[2], pb[2];
    auto load = [&](int kt) {
        const int kb = kt * BK;
#pragma unroll
        for (int j = 0; j < 2; ++j) {
            pa[j] = *(const int32x4*)(Aq + gaofs[j] + kb);
            pb[j] = *(const int32x4*)(W8 + gbofs[j] + kb);
        }
    };
    auto lwrite = [&](int buf) {
#pragma unroll
        for (int j = 0; j < 2; ++j) {
            *(int32x4*)(&As[buf][lofs[j]]) = pa[j];   // compiler: counted vmcnt
            *(int32x4*)(&Bs[buf][lofs[j]]) = pb[j];
        }
    };

    // prologue: fill buf0
    load(0);
    lwrite(0);
    asm volatile("s_waitcnt lgkmcnt(0)" ::: "memory");
    __builtin_amdgcn_s_barrier();

    for (int kt = 0; kt < KSTEPS; ++kt) {
        const int cur = kt & 1;
        if (kt + 1 < KSTEPS) load(kt + 1);       // issue early; lands under MFMA
        __builtin_amdgcn_sched_barrier(0);

        const signed char* Ab = As[cur];
        const signed char* Bb = Bs[cur];
        __builtin_amdgcn_s_setprio(1);
#pragma unroll
        for (int ks = 0; ks < 2; ++ks) {
            int32x4 af[2], bf[2];
#pragma unroll
            for (int mt = 0; mt < 2; ++mt) {
                const int rr = wm * 64 + mt * 32 + lr;
                const int pp = (ks * 2 + l5) ^ ((rr >> 1) & 3);
                af[mt] = *(const int32x4*)(Ab + (rr << 6) + (pp << 4));
            }
#pragma unroll
            for (int nt = 0; nt < 2; ++nt) {
                const int rr = wn * 64 + nt * 32 + lr;
                const int pp = (ks * 2 + l5) ^ ((rr >> 1) & 3);
                bf[nt] = *(const int32x4*)(Bb + (rr << 6) + (pp << 4));
            }
#pragma unroll
            for (int mt = 0; mt < 2; ++mt)
#pragma unroll
                for (int nt = 0; nt < 2; ++nt)
                    acc[mt][nt] = __builtin_amdgcn_mfma_i32_32x32x32_i8(
                        af[mt], bf[nt], acc[mt][nt], 0, 0, 0);
        }
        __builtin_amdgcn_s_setprio(0);

        if (kt + 1 < KSTEPS) lwrite(cur ^ 1);    // write next tile to other buf
        // ds_writes visible to all waves + all reads of buf[cur] complete
        asm volatile("s_waitcnt lgkmcnt(0)" ::: "memory");
        __builtin_amdgcn_s_barrier();
    }

    // epilogue: (acc + qb[n]) * dq[n] -> fp32, C-order [M,N]
    // C/D layout (HW-verified): col = lane&31, row = (reg&3)+8*(reg>>2)+4*(lane>>5)
    const Resolved rs = resolve4(p11a, p11b);
#pragma unroll
    for (int nt = 0; nt < 2; ++nt) {
        const int gn   = n0 + wn * 64 + nt * 32 + lr;
        const int qbn  = rs.qb[gn];
        const float dq = rs.dq[gn];
#pragma unroll
        for (int mt = 0; mt < 2; ++mt) {
            const int gmb = m0 + wm * 64 + mt * 32 + (l5 << 2);
#pragma unroll
            for (int v = 0; v < 16; ++v) {
                const int gm = gmb + (v & 3) + ((v >> 2) << 3);
                out[(size_t)gm * NDIM + gn] = (float)(acc[mt][nt][v] + qbn) * dq;
            }
        }
    }
}

__global__ void codek(float* __restrict__ out) {
    out[blockIdx.x * 64 + threadIdx.x] = 51200.f;
}

extern "C" void kernel_launch(void* const* d_in, const int* in_sizes, int n_in,
                              void* d_out, int out_size, void* d_ws, size_t ws_size,
                              hipStream_t stream) {
    float* out = (float*)d_out;

    // order-robust pointer resolution by size fingerprint
    int ix = -1, iw = -1, i11[2] = {-1, -1}, i1[2] = {-1, -1};
    int n11 = 0, n1 = 0;
    bool bad = (n_in != 6);
    for (int i = 0; i < n_in && !bad; ++i) {
        const int s = in_sizes[i];
        if (s == MDIM * KDIM && ix < 0) ix = i;
        else if (s == NDIM * KDIM && iw < 0) iw = i;
        else if (s == NDIM && n11 < 2) i11[n11++] = i;
        else if (s == 1 && n1 < 2) i1[n1++] = i;
        else bad = true;
    }
    const size_t xq_bytes = (size_t)MDIM * KDIM;  // 33.5 MB
    const size_t w8_bytes = (size_t)NDIM * KDIM;  // 45.1 MB
    if (bad || ix < 0 || iw < 0 || n11 != 2 || n1 != 2 ||
        ws_size < xq_bytes + w8_bytes) {
        codek<<<dim3(100), dim3(64), 0, stream>>>(out);
        return;
    }

    const float* X  = (const float*)d_in[ix];
    const int*   Wi = (const int*)d_in[iw];
    const void*  pa = d_in[i11[0]];
    const void*  pb = d_in[i11[1]];
    const void*  pc = d_in[i1[0]];
    const void*  pd = d_in[i1[1]];

    signed char* xq = (signed char*)d_ws;
    signed char* w8 = xq + xq_bytes;

    quant_x<<<dim3(2048), dim3(256), 0, stream>>>(X, pc, pd, xq);
    pack_w<<<dim3(2048), dim3(256), 0, stream>>>(Wi, w8);
    gemm_i8<<<dim3(NWG), dim3(256), 0, stream>>>(xq, w8, pa, pb, out);
}

// Round 22
// 588.124 us; speedup vs baseline: 14.4814x; 1.0099x over previous
//
#include <hip/hip_runtime.h>

// W8A8 static-quant linear, M=8192 K=4096 N=11008. out = fp32((xq@W^T + qb)*dq)
// Decode (validated R14-R21, absmax 0.5): x fp32[M,K]-C, W i32-widened i8
// [N,K]-C, dq f32[N], isc f32[1], qb i32[N], iof i32[1], out fp32[M,N]-C.
//
// R22 = TILED OPERAND LAYOUT. Elimination chain: staging=74% (R19); not HBM
// traffic (R20), not latency (R16), not LDS-DMA (R21), not schedule (R15/18).
// Shared culprit: every staging wave-load spans 16 rows x 64B (K-stride 4096)
// -> TA processes scattered lane-groups; measured ~18B/cyc/CU across ALL
// variants. Fix: prepasses write xq/w8 K-TILED (xqT[tile][kt][128r][64B] =
// contiguous 8KB per K-step tile) with the LDS XOR-swizzle baked in ->
// staging = wave-contiguous 1KB gload_lds (full lines, TA fast path).
// GEMM skeleton/LDS image/fragment reads byte-identical to R20.

#define MDIM 8192
#define KDIM 4096
#define NDIM 11008

#define BM 128
#define BN 128
#define BK 64
#define TM (MDIM / BM)      // 64
#define TN (NDIM / BN)      // 86
#define NWG (TM * TN)       // 5504
#define CPX (NWG / 8)       // 688
#define KSTEPS (KDIM / BK)  // 64
#define TILEB (BM * BK)     // 8192 bytes per K-step tile

using int32x4  = __attribute__((ext_vector_type(4))) int;
using int32x16 = __attribute__((ext_vector_type(16))) int;
using floatx4  = __attribute__((ext_vector_type(4))) float;

__device__ __forceinline__ void gload_lds16(const void* g, void* l) {
    __builtin_amdgcn_global_load_lds(
        (__attribute__((address_space(1))) unsigned int*)g,
        (__attribute__((address_space(3))) unsigned int*)l,
        16, 0, 0);
}

__device__ __forceinline__ int quant1(float f, float inv, float off) {
    float r = rintf(f * inv) + off;          // jnp: round half-even, then clip
    r = fminf(127.f, fmaxf(-128.f, r));
    return (int)r;
}

__device__ __forceinline__ int pack4i(int a, int b, int c, int d) {
    return (a & 255) | ((b & 255) << 8) | ((c & 255) << 16) | ((d & 255) << 24);
}

struct Resolved { const float* dq; const int* qb; };
__device__ __forceinline__ Resolved resolve4(const void* p11a, const void* p11b) {
    Resolved r;
    int a_is_dq = 1;
#pragma unroll
    for (int j = 0; j < 8; ++j) {
        const float v = ((const float*)p11a)[j];
        a_is_dq &= (v > 1e-6f) & (v < 1e-2f);   // deq ~1e-4; int bits: denorm/neg
    }
    r.dq = a_is_dq ? (const float*)p11a : (const float*)p11b;
    r.qb = a_is_dq ? (const int*)p11b : (const int*)p11a;
    return r;
}

__device__ __forceinline__ void resolve_scale(const void* p1a, const void* p1b,
                                              float* inv, float* off) {
    const float fa = ((const float*)p1a)[0];
    const int a_is_isc = (fa > 1e-3f) & (fa < 1.0f);  // isc in [0.02,0.045]
    const float iscv = a_is_isc ? ((const float*)p1a)[0] : ((const float*)p1b)[0];
    *inv = 1.0f / iscv;
    *off = (float)(a_is_isc ? ((const int*)p1b)[0] : ((const int*)p1a)[0]);
}

// ---- pass 1a: x fp32 -> int8, K-tiled + swizzle-baked ----
// xqT[mt][kt][r][64B]; physical 16B chunk p of row r holds logical chunk
// c = p ^ ((r>>1)&3)  (address-side XOR; matches GEMM fragment readers).
__global__ __launch_bounds__(256)
void quant_xT(const float* __restrict__ X, const void* p1a, const void* p1b,
              signed char* __restrict__ xqT) {
    float inv, off;
    resolve_scale(p1a, p1b, &inv, &off);
    const int mt   = blockIdx.x >> 4;       // 0..63
    const int slab = blockIdx.x & 15;       // 4 kt each
    const int t = threadIdx.x;
    const int r = t & 127, h = t >> 7;
    const float* src = X + (size_t)(mt * 128 + r) * KDIM;
    signed char* db  = xqT + (size_t)mt * (KSTEPS * TILEB) + r * 64;
    const int sw = (r >> 1) & 3;
#pragma unroll
    for (int it = 0; it < 2; ++it) {
        const int kt = slab * 4 + h + 2 * it;
        const float* s = src + kt * 64;
        int pk[16];
#pragma unroll
        for (int i = 0; i < 16; ++i) {
            floatx4 v = *(const floatx4*)(s + 4 * i);
            pk[i] = pack4i(quant1(v[0], inv, off), quant1(v[1], inv, off),
                           quant1(v[2], inv, off), quant1(v[3], inv, off));
        }
        signed char* d = db + (size_t)kt * TILEB;
#pragma unroll
        for (int c = 0; c < 4; ++c) {       // logical chunk c -> physical c^sw
            int32x4 o;
            o[0] = pk[c * 4]; o[1] = pk[c * 4 + 1];
            o[2] = pk[c * 4 + 2]; o[3] = pk[c * 4 + 3];
            *(int32x4*)(d + ((c ^ sw) << 4)) = o;
        }
    }
}

// ---- pass 1b: W int32-widened -> int8, K-tiled + swizzle-baked ----
__global__ __launch_bounds__(256)
void pack_wT(const int* __restrict__ Wi, signed char* __restrict__ w8T) {
    const int nt   = blockIdx.x >> 4;       // 0..85
    const int slab = blockIdx.x & 15;
    const int t = threadIdx.x;
    const int r = t & 127, h = t >> 7;
    const int* src = Wi + (size_t)(nt * 128 + r) * KDIM;
    signed char* db = w8T + (size_t)nt * (KSTEPS * TILEB) + r * 64;
    const int sw = (r >> 1) & 3;
#pragma unroll
    for (int it = 0; it < 2; ++it) {
        const int kt = slab * 4 + h + 2 * it;
        const int* s = src + kt * 64;
        int pk[16];
#pragma unroll
        for (int i = 0; i < 16; ++i) {
            int32x4 v = *(const int32x4*)(s + 4 * i);
            pk[i] = pack4i(v[0], v[1], v[2], v[3]);
        }
        signed char* d = db + (size_t)kt * TILEB;
#pragma unroll
        for (int c = 0; c < 4; ++c) {
            int32x4 o;
            o[0] = pk[c * 4]; o[1] = pk[c * 4 + 1];
            o[2] = pk[c * 4 + 2]; o[3] = pk[c * 4 + 3];
            *(int32x4*)(d + ((c ^ sw) << 4)) = o;
        }
    }
}

// -- pass 2: int8 MFMA GEMM; contiguous-tile staging; depth-2 counted vmcnt --
// LDS image and fragment addressing byte-identical to R20 (validated).
__global__ __launch_bounds__(256, 3)
void gemm_i8(const signed char* __restrict__ AqT, const signed char* __restrict__ W8T,
             const void* p11a, const void* p11b,
             float* __restrict__ out) {
    __shared__ alignas(16) signed char As[3][TILEB];   // 3 x 8KB
    __shared__ alignas(16) signed char Bs[3][TILEB];   // 3 x 8KB

    const int tid  = threadIdx.x;
    const int lane = tid & 63;
    const int wv   = tid >> 6;
    const int l5   = lane >> 5;
    const int lr   = lane & 31;
    const int wm   = wv >> 1;
    const int wn   = wv & 1;

    const int bid = blockIdx.x;
    const int wg  = (bid & 7) * CPX + (bid >> 3);   // bijective XCD chunking
    // grouped mapping (R20-validated): strips of 8 n-tiles (last 6), groups
    // of 8 m-tiles, n fastest inside a group.
    int s, r;
    if (wg < 5120) { s = wg >> 9; r = wg & 511; }
    else           { s = 10;      r = wg - 5120; }
    const int w  = (s < 10) ? 8 : 6;
    const int gs = w << 3;
    const int g  = r / gs;
    const int t  = r % gs;
    const int mtile = (g << 3) + t / w;
    const int ntile = s * 8 + t % w;
    const int m0 = mtile * BM;
    const int n0 = ntile * BN;

    const signed char* Abase = AqT + (size_t)mtile * (KSTEPS * TILEB);
    const signed char* Bbase = W8T + (size_t)ntile * (KSTEPS * TILEB);

    int32x16 acc[2][2];
#pragma unroll
    for (int i = 0; i < 2; ++i)
#pragma unroll
        for (int j = 0; j < 2; ++j)
#pragma unroll
            for (int e = 0; e < 16; ++e) acc[i][j][e] = 0;

    // stage: 4 wave-contiguous 1KB gload_lds per thread-group (2 A + 2 B)
    auto stage = [&](int buf, int kt) {
        const size_t ka = (size_t)kt * TILEB;
#pragma unroll
        for (int j = 0; j < 2; ++j) {
            const int co = (wv << 6) + (j << 8);        // chunk base (wave-uniform)
            gload_lds16(Abase + ka + ((co + lane) << 4), &As[buf][co << 4]);
            gload_lds16(Bbase + ka + ((co + lane) << 4), &Bs[buf][co << 4]);
        }
    };

    stage(0, 0);
    stage(1, 1);

    int cur = 0, nb2 = 2;
    for (int kt = 0; kt < KSTEPS; ++kt) {
        if (kt + 2 < KSTEPS) {
            stage(nb2, kt + 2);
            asm volatile("s_waitcnt vmcnt(8)" ::: "memory");
        } else if (kt + 1 < KSTEPS) {
            asm volatile("s_waitcnt vmcnt(4)" ::: "memory");
        } else {
            asm volatile("s_waitcnt vmcnt(0)" ::: "memory");
        }
        __builtin_amdgcn_s_barrier();
        __builtin_amdgcn_sched_barrier(0);

        const signed char* Ab = As[cur];
        const signed char* Bb = Bs[cur];
        __builtin_amdgcn_s_setprio(1);
#pragma unroll
        for (int ks = 0; ks < 2; ++ks) {
            int32x4 af[2], bf[2];
#pragma unroll
            for (int mt = 0; mt < 2; ++mt) {
                const int rr = wm * 64 + mt * 32 + lr;
                const int pp = (ks * 2 + l5) ^ ((rr >> 1) & 3);
                af[mt] = *(const int32x4*)(Ab + (rr << 6) + (pp << 4));
            }
#pragma unroll
            for (int nt = 0; nt < 2; ++nt) {
                const int rr = wn * 64 + nt * 32 + lr;
                const int pp = (ks * 2 + l5) ^ ((rr >> 1) & 3);
                bf[nt] = *(const int32x4*)(Bb + (rr << 6) + (pp << 4));
            }
#pragma unroll
            for (int mt = 0; mt < 2; ++mt)
#pragma unroll
                for (int nt = 0; nt < 2; ++nt)
                    acc[mt][nt] = __builtin_amdgcn_mfma_i32_32x32x32_i8(
                        af[mt], bf[nt], acc[mt][nt], 0, 0, 0);
        }
        __builtin_amdgcn_s_setprio(0);
        __builtin_amdgcn_s_barrier();

        cur = (cur == 2) ? 0 : cur + 1;
        nb2 = (nb2 == 2) ? 0 : nb2 + 1;
    }

    // epilogue: (acc + qb[n]) * dq[n] -> fp32, C-order [M,N]
    // C/D layout (HW-verified): col = lane&31, row = (reg&3)+8*(reg>>2)+4*(lane>>5)
    const Resolved rs = resolve4(p11a, p11b);
#pragma unroll
    for (int nt = 0; nt < 2; ++nt) {
        const int gn   = n0 + wn * 64 + nt * 32 + lr;
        const int qbn  = rs.qb[gn];
        const float dq = rs.dq[gn];
#pragma unroll
        for (int mt = 0; mt < 2; ++mt) {
            const int gmb = m0 + wm * 64 + mt * 32 + (l5 << 2);
#pragma unroll
            for (int v = 0; v < 16; ++v) {
                const int gm = gmb + (v & 3) + ((v >> 2) << 3);
                out[(size_t)gm * NDIM + gn] = (float)(acc[mt][nt][v] + qbn) * dq;
            }
        }
    }
}

__global__ void codek(float* __restrict__ out) {
    out[blockIdx.x * 64 + threadIdx.x] = 51200.f;
}

extern "C" void kernel_launch(void* const* d_in, const int* in_sizes, int n_in,
                              void* d_out, int out_size, void* d_ws, size_t ws_size,
                              hipStream_t stream) {
    float* out = (float*)d_out;

    // order-robust pointer resolution by size fingerprint
    int ix = -1, iw = -1, i11[2] = {-1, -1}, i1[2] = {-1, -1};
    int n11 = 0, n1 = 0;
    bool bad = (n_in != 6);
    for (int i = 0; i < n_in && !bad; ++i) {
        const int s = in_sizes[i];
        if (s == MDIM * KDIM && ix < 0) ix = i;
        else if (s == NDIM * KDIM && iw < 0) iw = i;
        else if (s == NDIM && n11 < 2) i11[n11++] = i;
        else if (s == 1 && n1 < 2) i1[n1++] = i;
        else bad = true;
    }
    const size_t xq_bytes = (size_t)MDIM * KDIM;  // 33.5 MB
    const size_t w8_bytes = (size_t)NDIM * KDIM;  // 45.1 MB
    if (bad || ix < 0 || iw < 0 || n11 != 2 || n1 != 2 ||
        ws_size < xq_bytes + w8_bytes) {
        codek<<<dim3(100), dim3(64), 0, stream>>>(out);
        return;
    }

    const float* X  = (const float*)d_in[ix];
    const int*   Wi = (const int*)d_in[iw];
    const void*  pa = d_in[i11[0]];
    const void*  pb = d_in[i11[1]];
    const void*  pc = d_in[i1[0]];
    const void*  pd = d_in[i1[1]];

    signed char* xqT = (signed char*)d_ws;
    signed char* w8T = xqT + xq_bytes;

    quant_xT<<<dim3(TM * 16), dim3(256), 0, stream>>>(X, pc, pd, xqT);
    pack_wT<<<dim3(TN * 16), dim3(256), 0, stream>>>(Wi, w8T);
    gemm_i8<<<dim3(NWG), dim3(256), 0, stream>>>(xqT, w8T, pa, pb, out);
}

// Round 23
// 538.726 us; speedup vs baseline: 15.8092x; 1.0917x over previous
//
#include <hip/hip_runtime.h>

// W8A8 static-quant linear, M=8192 K=4096 N=11008. out = fp32((xq@W^T + qb)*dq)
// Decode (validated R14-R22, absmax 0.5): x fp32[M,K]-C, W i32-widened i8
// [N,K]-C, dq f32[N], isc f32[1], qb i32[N], iof i32[1], out fp32[M,N]-C.
//
// R23 = ARITHMETIC-INTENSITY lever. Cross-kernel law (ours + m97 + m201):
// staging throughput pins at ~11-13 TB/s for ALL schedules; at equal bytes/op
// all land at the same op-rate. R15-R22 nulls explained. Fix: 256x128 tile
// (bytes/op 7.6e-3 -> 5.7e-3) at 512 thr / 8 waves / 2 blocks/CU, keeping the
// validated R16 depth-2 counted-vmcnt skeleton, R22 tiled prepasses (A panel =
// two stacked 128-row sub-panels; (rr>>1)&3 swizzle + rr*64 addressing hold
// for rr in [0,256)), 64x64 wave tile (acc[2][2], 4 waves/SIMD).

#define MDIM 8192
#define KDIM 4096
#define NDIM 11008

#define BM 256
#define BN 128
#define BK 64
#define TMS (MDIM / BM)     // 32 super-m tiles (2 prepass panels each)
#define TN (NDIM / BN)      // 86
#define NWG (TMS * TN)      // 2752 (div by 8)
#define CPX (NWG / 8)       // 344
#define KSTEPS (KDIM / BK)  // 64
#define PTILEB (128 * BK)   // 8192 B: prepass panel K-step tile

using int32x4  = __attribute__((ext_vector_type(4))) int;
using int32x16 = __attribute__((ext_vector_type(16))) int;
using floatx4  = __attribute__((ext_vector_type(4))) float;

__device__ __forceinline__ void gload_lds16(const void* g, void* l) {
    __builtin_amdgcn_global_load_lds(
        (__attribute__((address_space(1))) unsigned int*)g,
        (__attribute__((address_space(3))) unsigned int*)l,
        16, 0, 0);
}

__device__ __forceinline__ int quant1(float f, float inv, float off) {
    float r = rintf(f * inv) + off;          // jnp: round half-even, then clip
    r = fminf(127.f, fmaxf(-128.f, r));
    return (int)r;
}

__device__ __forceinline__ int pack4i(int a, int b, int c, int d) {
    return (a & 255) | ((b & 255) << 8) | ((c & 255) << 16) | ((d & 255) << 24);
}

struct Resolved { const float* dq; const int* qb; };
__device__ __forceinline__ Resolved resolve4(const void* p11a, const void* p11b) {
    Resolved r;
    int a_is_dq = 1;
#pragma unroll
    for (int j = 0; j < 8; ++j) {
        const float v = ((const float*)p11a)[j];
        a_is_dq &= (v > 1e-6f) & (v < 1e-2f);   // deq ~1e-4; int bits: denorm/neg
    }
    r.dq = a_is_dq ? (const float*)p11a : (const float*)p11b;
    r.qb = a_is_dq ? (const int*)p11b : (const int*)p11a;
    return r;
}

__device__ __forceinline__ void resolve_scale(const void* p1a, const void* p1b,
                                              float* inv, float* off) {
    const float fa = ((const float*)p1a)[0];
    const int a_is_isc = (fa > 1e-3f) & (fa < 1.0f);  // isc in [0.02,0.045]
    const float iscv = a_is_isc ? ((const float*)p1a)[0] : ((const float*)p1b)[0];
    *inv = 1.0f / iscv;
    *off = (float)(a_is_isc ? ((const int*)p1b)[0] : ((const int*)p1a)[0]);
}

// ---- pass 1a: x fp32 -> int8, K-tiled + swizzle-baked (R22-validated) ----
// xqT[panel][kt][r][64B]; physical chunk p of row r holds logical c = p ^ ((r>>1)&3)
__global__ __launch_bounds__(256)
void quant_xT(const float* __restrict__ X, const void* p1a, const void* p1b,
              signed char* __restrict__ xqT) {
    float inv, off;
    resolve_scale(p1a, p1b, &inv, &off);
    const int mt   = blockIdx.x >> 4;       // panel 0..63
    const int slab = blockIdx.x & 15;
    const int t = threadIdx.x;
    const int r = t & 127, h = t >> 7;
    const float* src = X + (size_t)(mt * 128 + r) * KDIM;
    signed char* db  = xqT + (size_t)mt * (KSTEPS * PTILEB) + r * 64;
    const int sw = (r >> 1) & 3;
#pragma unroll
    for (int it = 0; it < 2; ++it) {
        const int kt = slab * 4 + h + 2 * it;
        const float* sp = src + kt * 64;
        int pk[16];
#pragma unroll
        for (int i = 0; i < 16; ++i) {
            floatx4 v = *(const floatx4*)(sp + 4 * i);
            pk[i] = pack4i(quant1(v[0], inv, off), quant1(v[1], inv, off),
                           quant1(v[2], inv, off), quant1(v[3], inv, off));
        }
        signed char* d = db + (size_t)kt * PTILEB;
#pragma unroll
        for (int c = 0; c < 4; ++c) {
            int32x4 o;
            o[0] = pk[c * 4]; o[1] = pk[c * 4 + 1];
            o[2] = pk[c * 4 + 2]; o[3] = pk[c * 4 + 3];
            *(int32x4*)(d + ((c ^ sw) << 4)) = o;
        }
    }
}

// ---- pass 1b: W int32-widened -> int8, K-tiled + swizzle-baked ----
__global__ __launch_bounds__(256)
void pack_wT(const int* __restrict__ Wi, signed char* __restrict__ w8T) {
    const int nt   = blockIdx.x >> 4;       // panel 0..85
    const int slab = blockIdx.x & 15;
    const int t = threadIdx.x;
    const int r = t & 127, h = t >> 7;
    const int* src = Wi + (size_t)(nt * 128 + r) * KDIM;
    signed char* db = w8T + (size_t)nt * (KSTEPS * PTILEB) + r * 64;
    const int sw = (r >> 1) & 3;
#pragma unroll
    for (int it = 0; it < 2; ++it) {
        const int kt = slab * 4 + h + 2 * it;
        const int* sp = src + kt * 64;
        int pk[16];
#pragma unroll
        for (int i = 0; i < 16; ++i) {
            int32x4 v = *(const int32x4*)(sp + 4 * i);
            pk[i] = pack4i(v[0], v[1], v[2], v[3]);
        }
        signed char* d = db + (size_t)kt * PTILEB;
#pragma unroll
        for (int c = 0; c < 4; ++c) {
            int32x4 o;
            o[0] = pk[c * 4]; o[1] = pk[c * 4 + 1];
            o[2] = pk[c * 4 + 2]; o[3] = pk[c * 4 + 3];
            *(int32x4*)(d + ((c ^ sw) << 4)) = o;
        }
    }
}

// -- pass 2: 256x128 int8 MFMA GEMM, depth-2 counted vmcnt, 8 waves --
// As per buffer = 16KB: two stacked 128-row sub-panel images (validated
// layout); row rr in [0,256): addr = rr*64 + p*16, p = (ks*2+l5)^((rr>>1)&3).
// Bs per buffer = 8KB (one panel). Stage = 3 gload_lds/thread (2 A + 1 B).
__global__ __launch_bounds__(512, 4)
void gemm_i8(const signed char* __restrict__ AqT, const signed char* __restrict__ W8T,
             const void* p11a, const void* p11b,
             float* __restrict__ out) {
    __shared__ alignas(16) signed char As[3][BM * BK];   // 3 x 16KB
    __shared__ alignas(16) signed char Bs[3][BN * BK];   // 3 x 8KB

    const int tid  = threadIdx.x;
    const int lane = tid & 63;
    const int wv   = tid >> 6;       // 0..7
    const int l5   = lane >> 5;
    const int lr   = lane & 31;
    const int wm   = wv >> 1;        // 0..3 : 64-row band of 256
    const int wn   = wv & 1;         // 0..1 : 64-col band of 128

    const int bid = blockIdx.x;
    const int wg  = (bid & 7) * CPX + (bid >> 3);   // bijective XCD chunking
    // grouped mapping: strips of 8 n-tiles (last 6), groups of 8 super-m,
    // n fastest inside a group.
    int st, r;
    if (wg < 2560) { st = wg >> 8; r = wg & 255; }  // strips 0..9: 256 wg
    else           { st = 10;      r = wg - 2560; } // strip 10: 192 wg
    const int w  = (st < 10) ? 8 : 6;
    const int gs = w << 3;
    const int g  = r / gs;
    const int t  = r % gs;
    const int msuper = (g << 3) + t / w;            // 0..31
    const int ntile  = st * 8 + t % w;              // 0..85
    const int m0 = msuper * BM;
    const int n0 = ntile * BN;

    const signed char* Ap0 = AqT + (size_t)(2 * msuper)     * (KSTEPS * PTILEB);
    const signed char* Ap1 = AqT + (size_t)(2 * msuper + 1) * (KSTEPS * PTILEB);
    const signed char* Bp  = W8T + (size_t)ntile            * (KSTEPS * PTILEB);

    int32x16 acc[2][2];
#pragma unroll
    for (int i = 0; i < 2; ++i)
#pragma unroll
        for (int j = 0; j < 2; ++j)
#pragma unroll
            for (int e = 0; e < 16; ++e) acc[i][j][e] = 0;

    // stage: 3 wave-contiguous 1KB gload_lds (A panel0, A panel1, B)
    auto stage = [&](int buf, int kt) {
        const size_t ka = (size_t)kt * PTILEB;
        const int co = wv << 6;                       // wave chunk base
        gload_lds16(Ap0 + ka + ((co + lane) << 4), &As[buf][co << 4]);
        gload_lds16(Ap1 + ka + ((co + lane) << 4), &As[buf][(512 + co) << 4]);
        gload_lds16(Bp  + ka + ((co + lane) << 4), &Bs[buf][co << 4]);
    };

    stage(0, 0);
    stage(1, 1);

    int cur = 0, nb2 = 2;
    for (int kt = 0; kt < KSTEPS; ++kt) {
        if (kt + 2 < KSTEPS) {
            stage(nb2, kt + 2);
            // stage(kt) landed; stage(kt+1) 3 + stage(kt+2) 3 in flight
            asm volatile("s_waitcnt vmcnt(6)" ::: "memory");
        } else if (kt + 1 < KSTEPS) {
            asm volatile("s_waitcnt vmcnt(3)" ::: "memory");
        } else {
            asm volatile("s_waitcnt vmcnt(0)" ::: "memory");
        }
        __builtin_amdgcn_s_barrier();
        __builtin_amdgcn_sched_barrier(0);

        const signed char* Ab = As[cur];
        const signed char* Bb = Bs[cur];
        __builtin_amdgcn_s_setprio(1);
#pragma unroll
        for (int ks = 0; ks < 2; ++ks) {
            int32x4 af[2], bf[2];
#pragma unroll
            for (int mt = 0; mt < 2; ++mt) {
                const int rr = wm * 64 + mt * 32 + lr;          // 0..255
                const int pp = (ks * 2 + l5) ^ ((rr >> 1) & 3);
                af[mt] = *(const int32x4*)(Ab + (rr << 6) + (pp << 4));
            }
#pragma unroll
            for (int nt = 0; nt < 2; ++nt) {
                const int rr = wn * 64 + nt * 32 + lr;          // 0..127
                const int pp = (ks * 2 + l5) ^ ((rr >> 1) & 3);
                bf[nt] = *(const int32x4*)(Bb + (rr << 6) + (pp << 4));
            }
#pragma unroll
            for (int mt = 0; mt < 2; ++mt)
#pragma unroll
                for (int nt = 0; nt < 2; ++nt)
                    acc[mt][nt] = __builtin_amdgcn_mfma_i32_32x32x32_i8(
                        af[mt], bf[nt], acc[mt][nt], 0, 0, 0);
        }
        __builtin_amdgcn_s_setprio(0);
        __builtin_amdgcn_s_barrier();

        cur = (cur == 2) ? 0 : cur + 1;
        nb2 = (nb2 == 2) ? 0 : nb2 + 1;
    }

    // epilogue: (acc + qb[n]) * dq[n] -> fp32, C-order [M,N]
    // C/D layout (HW-verified): col = lane&31, row = (reg&3)+8*(reg>>2)+4*(lane>>5)
    const Resolved rs = resolve4(p11a, p11b);
#pragma unroll
    for (int nt = 0; nt < 2; ++nt) {
        const int gn   = n0 + wn * 64 + nt * 32 + lr;
        const int qbn  = rs.qb[gn];
        const float dq = rs.dq[gn];
#pragma unroll
        for (int mt = 0; mt < 2; ++mt) {
            const int gmb = m0 + wm * 64 + mt * 32 + (l5 << 2);
#pragma unroll
            for (int v = 0; v < 16; ++v) {
                const int gm = gmb + (v & 3) + ((v >> 2) << 3);
                out[(size_t)gm * NDIM + gn] = (float)(acc[mt][nt][v] + qbn) * dq;
            }
        }
    }
}

__global__ void codek(float* __restrict__ out) {
    out[blockIdx.x * 64 + threadIdx.x] = 51200.f;
}

extern "C" void kernel_launch(void* const* d_in, const int* in_sizes, int n_in,
                              void* d_out, int out_size, void* d_ws, size_t ws_size,
                              hipStream_t stream) {
    float* out = (float*)d_out;

    // order-robust pointer resolution by size fingerprint
    int ix = -1, iw = -1, i11[2] = {-1, -1}, i1[2] = {-1, -1};
    int n11 = 0, n1 = 0;
    bool bad = (n_in != 6);
    for (int i = 0; i < n_in && !bad; ++i) {
        const int s = in_sizes[i];
        if (s == MDIM * KDIM && ix < 0) ix = i;
        else if (s == NDIM * KDIM && iw < 0) iw = i;
        else if (s == NDIM && n11 < 2) i11[n11++] = i;
        else if (s == 1 && n1 < 2) i1[n1++] = i;
        else bad = true;
    }
    const size_t xq_bytes = (size_t)MDIM * KDIM;  // 33.5 MB
    const size_t w8_bytes = (size_t)NDIM * KDIM;  // 45.1 MB
    if (bad || ix < 0 || iw < 0 || n11 != 2 || n1 != 2 ||
        ws_size < xq_bytes + w8_bytes) {
        codek<<<dim3(100), dim3(64), 0, stream>>>(out);
        return;
    }

    const float* X  = (const float*)d_in[ix];
    const int*   Wi = (const int*)d_in[iw];
    const void*  pa = d_in[i11[0]];
    const void*  pb = d_in[i11[1]];
    const void*  pc = d_in[i1[0]];
    const void*  pd = d_in[i1[1]];

    signed char* xqT = (signed char*)d_ws;
    signed char* w8T = xqT + xq_bytes;

    quant_xT<<<dim3(64 * 16), dim3(256), 0, stream>>>(X, pc, pd, xqT);
    pack_wT<<<dim3(86 * 16), dim3(256), 0, stream>>>(Wi, w8T);
    gemm_i8<<<dim3(NWG), dim3(512), 0, stream>>>(xqT, w8T, pa, pb, out);
}